// Round 2
// baseline (192.962 us; speedup 1.0000x reference)
//
#include <hip/hip_runtime.h>

// AttentionSinkRope — f32 shifted-copy + constant-angle re-rotation.
//
// Shapes (float32 elements):
//   k_caches: [16][1][8][128][4064]  (head-dim rows, positions contiguous)
//   v_caches: [16][1][8][4064][128]  (positions rows, head-dim contiguous)
//   rerotation_cos/sin: [3932][64]   (all rows identical: angle = -128*theta_d)
//   out = new_k ++ new_v, float32.
//
// Algebra: rerotation_cos[p,d] = cos(n)cos(o)+sin(n)sin(o) = cos((NEW-ORIG)*theta_d)
// -> position-independent; row 0 of each table supplies the 64 (C,S) pairs.
// Shifting the keep region by 128 positions is a constant element offset:
// +128 within a K row, +128*128 for V rows.

#define LH      128           // 16 layers * 8 heads (B=1)
#define DDIM    128
#define CLEN    4064
#define SINKN   4
#define KEEPEND 3936          // SINK + KEEP
#define SHIFT   128           // ORIG_POS - NEW_POS
#define KELEMS  66584576ull   // LH * DDIM * CLEN

// grid (64 d-pairs, 128 lh), block 256. Each block handles rows 2d and 2d+1
// of one (layer,head); columns contiguous -> fully coalesced float4.
__global__ __launch_bounds__(256) void k_rope_kernel(
    const float* __restrict__ k,
    const float* __restrict__ rcos,
    const float* __restrict__ rsin,
    float* __restrict__ out)
{
    const int rp = blockIdx.x;           // head-dim pair index d = 0..63
    const int lh = blockIdx.y;           // layer*head
    const size_t rowA = (size_t)lh * ((size_t)DDIM * CLEN) + (size_t)(2 * rp) * CLEN;
    const float* srcA = k + rowA;        // row 2d   (real part)
    const float* srcB = srcA + CLEN;     // row 2d+1 (imag part)
    float* dstA = out + rowA;
    float* dstB = dstA + CLEN;

    const float C = rcos[rp];            // table row 0 (rows all identical)
    const float S = rsin[rp];

    for (int chunk = threadIdx.x; chunk < 1016; chunk += 256) {
        const int c0 = chunk * 4;
        if (chunk >= 984) {
            // evicted tail: zero pad (cols 3936..4063)
            float4 z = make_float4(0.f, 0.f, 0.f, 0.f);
            *(float4*)(dstA + c0) = z;
            *(float4*)(dstB + c0) = z;
        } else if (chunk == 0) {
            // sink: cols 0..3 straight copy
            *(float4*)(dstA) = *(const float4*)(srcA);
            *(float4*)(dstB) = *(const float4*)(srcB);
        } else {
            // keep: rotate, source shifted +128 positions
            float4 a = *(const float4*)(srcA + c0 + SHIFT);
            float4 b = *(const float4*)(srcB + c0 + SHIFT);
            float4 oa, ob;
            oa.x = a.x * C - b.x * S;  ob.x = a.x * S + b.x * C;
            oa.y = a.y * C - b.y * S;  ob.y = a.y * S + b.y * C;
            oa.z = a.z * C - b.z * S;  ob.z = a.z * S + b.z * C;
            oa.w = a.w * C - b.w * S;  ob.w = a.w * S + b.w * C;
            *(float4*)(dstA + c0) = oa;
            *(float4*)(dstB + c0) = ob;
        }
    }
}

// grid (508, 128), block 256. One float4 chunk per thread; 32 chunks per
// position row. Keep shift = +128 rows = +16384 elements.
__global__ __launch_bounds__(256) void v_copy_kernel(
    const float* __restrict__ v,
    float* __restrict__ out)
{
    const int lh = blockIdx.y;
    const size_t base = (size_t)lh * ((size_t)CLEN * DDIM);
    const int idx = blockIdx.x * 256 + threadIdx.x;   // chunk id < 130048
    const int row = idx >> 5;                         // 32 chunks per row
    const size_t off = base + (size_t)idx * 4;
    float4 val;
    if (row < SINKN) {
        val = *(const float4*)(v + off);
    } else if (row < KEEPEND) {
        val = *(const float4*)(v + off + (size_t)SHIFT * DDIM);
    } else {
        val = make_float4(0.f, 0.f, 0.f, 0.f);
    }
    *(float4*)(out + off) = val;
}

extern "C" void kernel_launch(void* const* d_in, const int* in_sizes, int n_in,
                              void* d_out, int out_size, void* d_ws, size_t ws_size,
                              hipStream_t stream) {
    const float* k  = (const float*)d_in[0];
    const float* v  = (const float*)d_in[1];
    const float* rc = (const float*)d_in[2];
    const float* rs = (const float*)d_in[3];
    float* outk = (float*)d_out;
    float* outv = outk + KELEMS;

    hipLaunchKernelGGL(k_rope_kernel, dim3(64, 128), dim3(256), 0, stream,
                       k, rc, rs, outk);
    hipLaunchKernelGGL(v_copy_kernel, dim3(508, 128), dim3(256), 0, stream,
                       v, outv);
}